// Round 3
// baseline (205.063 us; speedup 1.0000x reference)
//
#include <hip/hip_runtime.h>

#define BLK 256
#define IPER 8
#define TJ 256
#define S_SLICES 16  // j-slices per direction

// Monotonic float<->uint mapping so uint atomicMin == float min (handles negatives).
__device__ __forceinline__ unsigned int fmap(float f) {
  unsigned int b = __float_as_uint(f);
  return (b & 0x80000000u) ? ~b : (b | 0x80000000u);
}
__device__ __forceinline__ float funmap(unsigned int u) {
  return __uint_as_float((u & 0x80000000u) ? (u ^ 0x80000000u) : ~u);
}

// Single fused kernel: both chamfer directions + last-block final reduce.
// blockIdx.z in [0,2B): dir = z/B (0: P=in,Q=tgt -> dist1; 1: P=tgt,Q=in -> dist2).
// Each block min-reduces its j-slice of (|q_j|^2 - 2 p_i . q_j) for IPER*BLK
// i-points, atomicMin's into umin. |p_i|^2 is added in the final reduce
// (doesn't affect the argmin). The LAST block to finish (device-scope counter)
// re-reads all mins and writes the scalar mean.
__global__ __launch_bounds__(BLK) void cl_nn(
    const float* __restrict__ A, const float* __restrict__ Bp,
    unsigned int* __restrict__ umin, unsigned int* __restrict__ counter,
    float* __restrict__ out, int N, int jslice, int Bn, int nblocks) {
  __shared__ float4 sq[TJ];
  const int z = blockIdx.z;
  const int dir = z / Bn;
  const int b = z - dir * Bn;
  const float* __restrict__ P = dir ? Bp : A;
  const float* __restrict__ Q = dir ? A : Bp;
  unsigned int* __restrict__ um = umin + ((size_t)dir * Bn + b) * N;

  const int t = threadIdx.x;
  const int ibase = blockIdx.x * (BLK * IPER);
  const int jbase = blockIdx.y * jslice;
  const size_t boff = (size_t)b * 3 * N;

  float m0[IPER], m1[IPER], m2[IPER], best[IPER];
#pragma unroll
  for (int k = 0; k < IPER; ++k) {
    int i = ibase + k * BLK + t;
    m0[k] = -2.0f * P[boff + i];
    m1[k] = -2.0f * P[boff + N + i];
    m2[k] = -2.0f * P[boff + 2 * N + i];
    best[k] = 3.0e38f;
  }

  for (int jb = 0; jb < jslice; jb += TJ) {
    int j = jbase + jb + t;
    float qx = Q[boff + j];
    float qy = Q[boff + N + j];
    float qz = Q[boff + 2 * N + j];
    float nq = fmaf(qz, qz, fmaf(qy, qy, qx * qx));
    __syncthreads();  // protect previous tile's readers
    sq[t] = make_float4(qx, qy, qz, nq);
    __syncthreads();
    // 4 q-points x IPER=8 i-points per iteration: 32 independent fma chains,
    // 0.125 ds_read_b128 per pair, min-tree shaped for v_min3_f32 fusion.
    for (int jj = 0; jj < TJ; jj += 4) {
      float4 q0 = sq[jj + 0];
      float4 q1 = sq[jj + 1];
      float4 q2 = sq[jj + 2];
      float4 q3 = sq[jj + 3];
#pragma unroll
      for (int k = 0; k < IPER; ++k) {
        float t0 = fmaf(m2[k], q0.z, fmaf(m1[k], q0.y, fmaf(m0[k], q0.x, q0.w)));
        float t1 = fmaf(m2[k], q1.z, fmaf(m1[k], q1.y, fmaf(m0[k], q1.x, q1.w)));
        float t2 = fmaf(m2[k], q2.z, fmaf(m1[k], q2.y, fmaf(m0[k], q2.x, q2.w)));
        float t3 = fmaf(m2[k], q3.z, fmaf(m1[k], q3.y, fmaf(m0[k], q3.x, q3.w)));
        best[k] = fminf(fminf(best[k], fminf(t0, t1)), fminf(t2, t3));
      }
    }
  }
#pragma unroll
  for (int k = 0; k < IPER; ++k) {
    int i = ibase + k * BLK + t;
    atomicMin(&um[i], fmap(best[k]));
  }

  // ---- last-block-done final reduction ----
  __syncthreads();  // drains this block's vmem (atomicMins) before the vote
  __shared__ unsigned int is_last;
  if (t == 0) {
    unsigned int prev = __hip_atomic_fetch_add(counter, 1u, __ATOMIC_ACQ_REL,
                                               __HIP_MEMORY_SCOPE_AGENT);
    is_last = (prev == (unsigned int)(nblocks - 1)) ? 1u : 0u;
  }
  __syncthreads();
  if (!is_last) return;

  // One block: decode all 2*B*N mins, add |p|^2, sum in double, write mean.
  double s = 0.0;
  for (int d = 0; d < 2; ++d) {
    const float* __restrict__ Pp = d ? Bp : A;
    for (int bb = 0; bb < Bn; ++bb) {
      const size_t bo = (size_t)bb * 3 * N;
      const unsigned int* __restrict__ uu = umin + ((size_t)d * Bn + bb) * N;
      for (int i = t; i < N; i += BLK) {
        float x = Pp[bo + i], y = Pp[bo + N + i], zc = Pp[bo + 2 * N + i];
        float np = fmaf(zc, zc, fmaf(y, y, x * x));
        unsigned int uv = __hip_atomic_load(&uu[i], __ATOMIC_RELAXED,
                                            __HIP_MEMORY_SCOPE_AGENT);
        s += (double)(funmap(uv) + np);
      }
    }
  }
  for (int off = 32; off > 0; off >>= 1) s += __shfl_down(s, off, 64);
  __shared__ double sw[BLK / 64];
  if ((t & 63) == 0) sw[t >> 6] = s;
  __syncthreads();
  if (t == 0) {
    double tot = 0.0;
    for (int w = 0; w < BLK / 64; ++w) tot += sw[w];
    out[0] = (float)(tot / (2.0 * (double)Bn * (double)N));
  }
}

extern "C" void kernel_launch(void* const* d_in, const int* in_sizes, int n_in,
                              void* d_out, int out_size, void* d_ws, size_t ws_size,
                              hipStream_t stream) {
  const float* in_pc = (const float*)d_in[0];
  const float* tgt_pc = (const float*)d_in[1];
  const int B = 2, N = 16384;
  unsigned int* u = (unsigned int*)d_ws;          // [2][B][N] uints = 256 KB
  unsigned int* counter = u + (size_t)2 * B * N;  // 1 uint

  // 0xFF bytes == 0xFFFFFFFF == "+inf" under fmap ordering; counter = 0.
  hipMemsetAsync(u, 0xFF, (size_t)2 * B * N * sizeof(unsigned int), stream);
  hipMemsetAsync(counter, 0, sizeof(unsigned int), stream);

  const int jslice = N / S_SLICES;                       // 1024
  dim3 grid(N / (BLK * IPER), S_SLICES, 2 * B);          // (8,16,4) = 512 blocks
  const int nblocks = grid.x * grid.y * grid.z;
  cl_nn<<<grid, dim3(BLK), 0, stream>>>(in_pc, tgt_pc, u, counter,
                                        (float*)d_out, N, jslice, B, nblocks);
}

// Round 4
// 141.759 us; speedup vs baseline: 1.4466x; 1.4466x over previous
//
#include <hip/hip_runtime.h>

#define BLK 256
#define IPER 4
#define TJ 256
#define S_SLICES 32  // j-slices per direction -> 2048 blocks = 8 waves/SIMD

// Monotonic float<->uint mapping so uint atomicMin == float min (handles negatives).
__device__ __forceinline__ unsigned int fmap(float f) {
  unsigned int b = __float_as_uint(f);
  return (b & 0x80000000u) ? ~b : (b | 0x80000000u);
}
__device__ __forceinline__ float funmap(unsigned int u) {
  return __uint_as_float((u & 0x80000000u) ? (u ^ 0x80000000u) : ~u);
}

// Both chamfer directions in one launch. blockIdx.z in [0,2B):
//   dir = z/B: 0 -> P=in,Q=tgt (dist1); 1 -> P=tgt,Q=in (dist2)
// For each i in P: min over this block's j-slice of (|q_j|^2 - 2 p_i . q_j);
// |p_i|^2 added in cl_reduce (doesn't affect the argmin).
__global__ __launch_bounds__(BLK) void cl_nn(
    const float* __restrict__ A, const float* __restrict__ Bp,
    unsigned int* __restrict__ umin, int N, int jslice, int Bn) {
  __shared__ float4 sq[TJ];
  const int z = blockIdx.z;
  const int dir = z / Bn;
  const int b = z - dir * Bn;
  const float* __restrict__ P = dir ? Bp : A;
  const float* __restrict__ Q = dir ? A : Bp;
  unsigned int* __restrict__ um = umin + ((size_t)dir * Bn + b) * N;

  const int t = threadIdx.x;
  const int ibase = blockIdx.x * (BLK * IPER);
  const int jbase = blockIdx.y * jslice;
  const size_t boff = (size_t)b * 3 * N;

  float m0[IPER], m1[IPER], m2[IPER], best[IPER];
#pragma unroll
  for (int k = 0; k < IPER; ++k) {
    int i = ibase + k * BLK + t;
    m0[k] = -2.0f * P[boff + i];
    m1[k] = -2.0f * P[boff + N + i];
    m2[k] = -2.0f * P[boff + 2 * N + i];
    best[k] = 3.0e38f;
  }

  for (int jb = 0; jb < jslice; jb += TJ) {
    int j = jbase + jb + t;
    float qx = Q[boff + j];
    float qy = Q[boff + N + j];
    float qz = Q[boff + 2 * N + j];
    float nq = fmaf(qz, qz, fmaf(qy, qy, qx * qx));
    __syncthreads();  // protect previous tile's readers
    sq[t] = make_float4(qx, qy, qz, nq);
    __syncthreads();
    // 4 q-points x IPER=4 i-points per iteration: 16 independent fma chains,
    // min-tree shaped for v_min3_f32 fusion. (Proven 96us @ 31% occ in R2;
    // this round only raises occupancy via the grid.)
    for (int jj = 0; jj < TJ; jj += 4) {
      float4 q0 = sq[jj + 0];
      float4 q1 = sq[jj + 1];
      float4 q2 = sq[jj + 2];
      float4 q3 = sq[jj + 3];
#pragma unroll
      for (int k = 0; k < IPER; ++k) {
        float t0 = fmaf(m2[k], q0.z, fmaf(m1[k], q0.y, fmaf(m0[k], q0.x, q0.w)));
        float t1 = fmaf(m2[k], q1.z, fmaf(m1[k], q1.y, fmaf(m0[k], q1.x, q1.w)));
        float t2 = fmaf(m2[k], q2.z, fmaf(m1[k], q2.y, fmaf(m0[k], q2.x, q2.w)));
        float t3 = fmaf(m2[k], q3.z, fmaf(m1[k], q3.y, fmaf(m0[k], q3.x, q3.w)));
        best[k] = fminf(fminf(best[k], fminf(t0, t1)), fminf(t2, t3));
      }
    }
  }
#pragma unroll
  for (int k = 0; k < IPER; ++k) {
    int i = ibase + k * BLK + t;
    atomicMin(&um[i], fmap(best[k]));
  }
}

// Parallel final reduce: 32 blocks, per-thread double partials over the
// 2*B*N min entries (+|p|^2), block reduce, one scaled float atomicAdd each.
__global__ __launch_bounds__(BLK) void cl_reduce(
    const float* __restrict__ in_pc, const float* __restrict__ tgt_pc,
    const unsigned int* __restrict__ u, float* __restrict__ out, int N, int Bn) {
  const int t = threadIdx.x;
  const int total = 2 * Bn * N;
  const int gid = blockIdx.x * BLK + t;
  const int gstride = gridDim.x * BLK;
  double s = 0.0;
  for (int idx = gid; idx < total; idx += gstride) {
    int dir = idx / (Bn * N);
    int rem = idx - dir * (Bn * N);
    int b = rem / N;
    int i = rem - b * N;
    const float* Pp = dir ? tgt_pc : in_pc;
    size_t boff = (size_t)b * 3 * N;
    float x = Pp[boff + i], y = Pp[boff + N + i], zc = Pp[boff + 2 * N + i];
    float np = fmaf(zc, zc, fmaf(y, y, x * x));
    s += (double)(funmap(u[idx]) + np);
  }
  for (int off = 32; off > 0; off >>= 1) s += __shfl_down(s, off, 64);
  __shared__ double sw[BLK / 64];
  if ((t & 63) == 0) sw[t >> 6] = s;
  __syncthreads();
  if (t == 0) {
    double tot = 0.0;
    for (int w = 0; w < BLK / 64; ++w) tot += sw[w];
    atomicAdd(out, (float)(tot / (2.0 * (double)Bn * (double)N)));
  }
}

extern "C" void kernel_launch(void* const* d_in, const int* in_sizes, int n_in,
                              void* d_out, int out_size, void* d_ws, size_t ws_size,
                              hipStream_t stream) {
  const float* in_pc = (const float*)d_in[0];
  const float* tgt_pc = (const float*)d_in[1];
  const int B = 2, N = 16384;
  unsigned int* u = (unsigned int*)d_ws;  // [2][B][N] uints = 256 KB
  float* out = (float*)d_out;

  // 0xFF bytes == 0xFFFFFFFF == "+inf" under fmap ordering; out accumulates.
  hipMemsetAsync(u, 0xFF, (size_t)2 * B * N * sizeof(unsigned int), stream);
  hipMemsetAsync(out, 0, sizeof(float), stream);

  const int jslice = N / S_SLICES;                   // 512
  dim3 grid(N / (BLK * IPER), S_SLICES, 2 * B);      // (16,32,4) = 2048 blocks
  cl_nn<<<grid, dim3(BLK), 0, stream>>>(in_pc, tgt_pc, u, N, jslice, B);

  cl_reduce<<<dim3(32), dim3(BLK), 0, stream>>>(in_pc, tgt_pc, u, out, N, B);
}

// Round 5
// 123.854 us; speedup vs baseline: 1.6557x; 1.1446x over previous
//
#include <hip/hip_runtime.h>

#define BLK 256
#define WAVES 4
#define MT 32            // mfma tile edge
#define IB (WAVES * MT)  // 128 i-points per block
#define TJQ 256          // q points staged per LDS chunk
#define SJ 4             // j-slices per (dir,b)

typedef __attribute__((ext_vector_type(8))) short short8;
typedef __attribute__((ext_vector_type(16))) float f32x16;

// Monotonic float<->uint mapping so uint atomicMin == float min (handles negatives).
__device__ __forceinline__ unsigned int fmap(float f) {
  unsigned int b = __float_as_uint(f);
  return (b & 0x80000000u) ? ~b : (b | 0x80000000u);
}
__device__ __forceinline__ float funmap(unsigned int u) {
  return __uint_as_float((u & 0x80000000u) ? (u ^ 0x80000000u) : ~u);
}
// RNE float->bf16 and back.
__device__ __forceinline__ unsigned short f2bf(float f) {
  unsigned int u = __float_as_uint(f);
  u += 0x7FFFu + ((u >> 16) & 1u);
  return (unsigned short)(u >> 16);
}
__device__ __forceinline__ float bf2f(unsigned short h) {
  return __uint_as_float(((unsigned int)h) << 16);
}
__device__ __forceinline__ unsigned int pk(unsigned short a, unsigned short b) {
  return (unsigned int)a | ((unsigned int)b << 16);
}

union FragU { uint4 u; short8 s; };

// D_ij = |q_j|^2 - 2 p_i.q_j via ONE mfma_f32_32x32x16_bf16 per 32x32 tile.
// K-slot layout (same slot index in A-vec and B-vec multiplies together):
//  A: [p2hx p2hy p2hz | p2lx p2ly p2lz | p2hx p2hy p2hz | p2lx p2ly p2lz | 1 1 1 | 0]
//  B: [ qhx  qhy  qhz |  qhx  qhy  qhz |  qlx  qly  qlz |  qlx  qly  qlz | nh nm nl | 0]
// where p2 = -2p split hi/lo (bf16), q split hi/lo, nq = |q|^2 triple-split.
// Sum = (p2h+p2l).(qh+ql) + nq  ~=  nq - 2 p.q  (residual ~2^-18 * magnitudes).
// |p_i|^2 is added (fp32) at the epilogue before atomicMin.
__global__ __launch_bounds__(BLK) void cl_mfma(
    const float* __restrict__ A, const float* __restrict__ Bp,
    unsigned int* __restrict__ umin, int N, int jslice, int Bn) {
  __shared__ uint4 sA[2][IB];   // A-vec halves: [g][point] 16B each (conflict-free b128)
  __shared__ uint4 sB[2][TJQ];  // B-vec halves
  __shared__ float sNP[IB];     // |p|^2 per i

  const int zi = blockIdx.z;
  const int dir = zi / Bn;
  const int b = zi - dir * Bn;
  const float* __restrict__ P = dir ? Bp : A;
  const float* __restrict__ Q = dir ? A : Bp;
  unsigned int* __restrict__ um = umin + ((size_t)dir * Bn + b) * N;

  const int t = threadIdx.x;
  const int ib0 = blockIdx.x * IB;
  const int jbase = blockIdx.y * jslice;
  const size_t boff = (size_t)b * 3 * N;
  const unsigned short one = 0x3F80u;  // bf16(1.0)

  // ---- stage A-vectors + |p|^2 (once) ----
  if (t < IB) {
    int i = ib0 + t;
    float x = P[boff + i], y = P[boff + N + i], zz = P[boff + 2 * N + i];
    float ax = -2.f * x, ay = -2.f * y, az = -2.f * zz;
    unsigned short hx = f2bf(ax), hy = f2bf(ay), hz = f2bf(az);
    unsigned short lx = f2bf(ax - bf2f(hx)), ly = f2bf(ay - bf2f(hy)),
                   lz = f2bf(az - bf2f(hz));
    sA[0][t] = make_uint4(pk(hx, hy), pk(hz, lx), pk(ly, lz), pk(hx, hy));
    sA[1][t] = make_uint4(pk(hz, lx), pk(ly, lz), pk(one, one), pk(one, 0));
    sNP[t] = fmaf(zz, zz, fmaf(y, y, x * x));
  }
  __syncthreads();

  const int w = t >> 6, l = t & 63, m = l & 31, g = l >> 5;
  FragU au; au.u = sA[g][w * MT + m];
  const short8 af = au.s;

  f32x16 run, zc;
#pragma unroll
  for (int r = 0; r < 16; ++r) { run[r] = 3.0e38f; zc[r] = 0.0f; }

  for (int ch = 0; ch < jslice / TJQ; ++ch) {
    __syncthreads();  // protect previous chunk's readers
    {
      int j = jbase + ch * TJQ + t;
      float x = Q[boff + j], y = Q[boff + N + j], zz = Q[boff + 2 * N + j];
      unsigned short hx = f2bf(x), hy = f2bf(y), hz = f2bf(zz);
      unsigned short lx = f2bf(x - bf2f(hx)), ly = f2bf(y - bf2f(hy)),
                     lz = f2bf(zz - bf2f(hz));
      float nq = fmaf(zz, zz, fmaf(y, y, x * x));
      unsigned short nh = f2bf(nq);
      float r1 = nq - bf2f(nh);
      unsigned short nm = f2bf(r1);
      unsigned short nl = f2bf(r1 - bf2f(nm));
      sB[0][t] = make_uint4(pk(hx, hy), pk(hz, hx), pk(hy, hz), pk(lx, ly));
      sB[1][t] = make_uint4(pk(lz, lx), pk(ly, lz), pk(nh, nm), pk(nl, 0));
    }
    __syncthreads();
#pragma unroll
    for (int jt = 0; jt < TJQ / MT; ++jt) {
      FragU bu; bu.u = sB[g][jt * MT + m];
      f32x16 d = __builtin_amdgcn_mfma_f32_32x32x16_bf16(af, bu.s, zc, 0, 0, 0);
#pragma unroll
      for (int r = 0; r < 16; ++r) run[r] = fminf(run[r], d[r]);
    }
  }

  // ---- epilogue: min across the 32 cols (lanes of same g), add |p|^2, atomicMin ----
  // C/D layout (m74/m101 verified): col=lane&31, row=(reg&3)+8*(reg>>2)+4*(lane>>5)
#pragma unroll
  for (int r = 0; r < 16; ++r) {
    float v = run[r];
    v = fminf(v, __shfl_xor(v, 1));
    v = fminf(v, __shfl_xor(v, 2));
    v = fminf(v, __shfl_xor(v, 4));
    v = fminf(v, __shfl_xor(v, 8));
    v = fminf(v, __shfl_xor(v, 16));
    if (m == 0) {
      int row = (r & 3) + 8 * (r >> 2) + 4 * g;
      int il = w * MT + row;
      atomicMin(&um[ib0 + il], fmap(v + sNP[il]));
    }
  }
}

// Parallel final reduce: umin already holds full squared distances.
__global__ __launch_bounds__(BLK) void cl_reduce(
    const unsigned int* __restrict__ u, float* __restrict__ out, int total,
    float inv) {
  const int t = threadIdx.x;
  const int gid = blockIdx.x * BLK + t;
  const int gstride = gridDim.x * BLK;
  double s = 0.0;
  for (int idx = gid; idx < total; idx += gstride) s += (double)funmap(u[idx]);
  for (int off = 32; off > 0; off >>= 1) s += __shfl_down(s, off, 64);
  __shared__ double sw[BLK / 64];
  if ((t & 63) == 0) sw[t >> 6] = s;
  __syncthreads();
  if (t == 0) {
    double tot = 0.0;
    for (int wv = 0; wv < BLK / 64; ++wv) tot += sw[wv];
    atomicAdd(out, (float)(tot * (double)inv));
  }
}

extern "C" void kernel_launch(void* const* d_in, const int* in_sizes, int n_in,
                              void* d_out, int out_size, void* d_ws, size_t ws_size,
                              hipStream_t stream) {
  const float* in_pc = (const float*)d_in[0];
  const float* tgt_pc = (const float*)d_in[1];
  const int B = 2, N = 16384;
  unsigned int* u = (unsigned int*)d_ws;  // [2][B][N] uints = 256 KB
  float* out = (float*)d_out;

  // 0xFF bytes == "+inf" under fmap ordering; out accumulates partials.
  hipMemsetAsync(u, 0xFF, (size_t)2 * B * N * sizeof(unsigned int), stream);
  hipMemsetAsync(out, 0, sizeof(float), stream);

  const int jslice = N / SJ;               // 4096
  dim3 grid(N / IB, SJ, 2 * B);            // (128,4,4) = 2048 blocks
  cl_mfma<<<grid, dim3(BLK), 0, stream>>>(in_pc, tgt_pc, u, N, jslice, B);

  const int total = 2 * B * N;
  cl_reduce<<<dim3(32), dim3(BLK), 0, stream>>>(u, out, total,
                                                1.0f / (float)total);
}

// Round 6
// 104.833 us; speedup vs baseline: 1.9561x; 1.1814x over previous
//
#include <hip/hip_runtime.h>

#define BLK 512
#define MT 32            // mfma tile edge
#define IB 256           // i-points per block (8 waves x 32)
#define TJQ 512          // q points staged per LDS chunk
#define SJ 4             // j-slices per (dir,b)

typedef __attribute__((ext_vector_type(8))) short short8;
typedef __attribute__((ext_vector_type(16))) float f32x16;

// Monotonic float<->uint mapping so uint atomicMin == float min (handles negatives).
__device__ __forceinline__ unsigned int fmap(float f) {
  unsigned int b = __float_as_uint(f);
  return (b & 0x80000000u) ? ~b : (b | 0x80000000u);
}
__device__ __forceinline__ float funmap(unsigned int u) {
  return __uint_as_float((u & 0x80000000u) ? (u ^ 0x80000000u) : ~u);
}
// RNE float->bf16 and back.
__device__ __forceinline__ unsigned short f2bf(float f) {
  unsigned int u = __float_as_uint(f);
  u += 0x7FFFu + ((u >> 16) & 1u);
  return (unsigned short)(u >> 16);
}
__device__ __forceinline__ float bf2f(unsigned short h) {
  return __uint_as_float(((unsigned int)h) << 16);
}
__device__ __forceinline__ unsigned int pk(unsigned short a, unsigned short b) {
  return (unsigned int)a | ((unsigned int)b << 16);
}

union FragU { uint4 u; short8 s; };

// D_ij = |q_j|^2 - 2 p_i.q_j via mfma_f32_32x32x16_bf16, split-bf16 compensated
// (same verified k-slot layout as round 5). Tiles processed in PAIRS so the
// running min uses v_min3_f32 (0.5 lane-ops/pair). launch_bounds(.,4) gives a
// 128-VGPR budget so accumulators stay in arch VGPRs (no accvgpr round-trip).
__global__ __launch_bounds__(BLK, 4) void cl_mfma(
    const float* __restrict__ A, const float* __restrict__ Bp,
    unsigned int* __restrict__ umin, int N, int jslice, int Bn) {
  __shared__ uint4 sA[2][IB];
  __shared__ uint4 sB[2][TJQ];
  __shared__ float sNP[IB];

  const int zi = blockIdx.z;
  const int dir = zi / Bn;
  const int b = zi - dir * Bn;
  const float* __restrict__ P = dir ? Bp : A;
  const float* __restrict__ Q = dir ? A : Bp;
  unsigned int* __restrict__ um = umin + ((size_t)dir * Bn + b) * N;

  const int t = threadIdx.x;
  const int ib0 = blockIdx.x * IB;
  const int jbase = blockIdx.y * jslice;
  const size_t boff = (size_t)b * 3 * N;
  const unsigned short one = 0x3F80u;  // bf16(1.0)

  // ---- stage A-vectors + |p|^2 (once) ----
  if (t < IB) {
    int i = ib0 + t;
    float x = P[boff + i], y = P[boff + N + i], zz = P[boff + 2 * N + i];
    float ax = -2.f * x, ay = -2.f * y, az = -2.f * zz;
    unsigned short hx = f2bf(ax), hy = f2bf(ay), hz = f2bf(az);
    unsigned short lx = f2bf(ax - bf2f(hx)), ly = f2bf(ay - bf2f(hy)),
                   lz = f2bf(az - bf2f(hz));
    sA[0][t] = make_uint4(pk(hx, hy), pk(hz, lx), pk(ly, lz), pk(hx, hy));
    sA[1][t] = make_uint4(pk(hz, lx), pk(ly, lz), pk(one, one), pk(one, 0));
    sNP[t] = fmaf(zz, zz, fmaf(y, y, x * x));
  }
  __syncthreads();

  const int w = t >> 6, l = t & 63, m = l & 31, g = l >> 5;
  FragU au; au.u = sA[g][w * MT + m];
  const short8 af = au.s;

  f32x16 run, zc;
#pragma unroll
  for (int r = 0; r < 16; ++r) { run[r] = 3.0e38f; zc[r] = 0.0f; }

  const int nch = jslice / TJQ;
  // software-pipelined q loads: chunk 0 preloaded here
  float qx = Q[boff + jbase + t];
  float qy = Q[boff + N + jbase + t];
  float qz = Q[boff + 2 * N + jbase + t];

  for (int ch = 0; ch < nch; ++ch) {
    // convert current chunk's q (registers only)
    unsigned short hx = f2bf(qx), hy = f2bf(qy), hz = f2bf(qz);
    unsigned short lx = f2bf(qx - bf2f(hx)), ly = f2bf(qy - bf2f(hy)),
                   lz = f2bf(qz - bf2f(hz));
    float nq = fmaf(qz, qz, fmaf(qy, qy, qx * qx));
    unsigned short nh = f2bf(nq);
    float r1 = nq - bf2f(nh);
    unsigned short nm = f2bf(r1);
    unsigned short nl = f2bf(r1 - bf2f(nm));
    uint4 b0 = make_uint4(pk(hx, hy), pk(hz, hx), pk(hy, hz), pk(lx, ly));
    uint4 b1 = make_uint4(pk(lz, lx), pk(ly, lz), pk(nh, nm), pk(nl, 0));

    __syncthreads();  // previous chunk fully consumed
    sB[0][t] = b0;
    sB[1][t] = b1;
    // issue next chunk's loads now; latency hides under the 16 tiles below
    {
      int jn = (ch + 1 < nch) ? (jbase + (ch + 1) * TJQ + t) : (jbase + t);
      qx = Q[boff + jn];
      qy = Q[boff + N + jn];
      qz = Q[boff + 2 * N + jn];
    }
    __syncthreads();

#pragma unroll 2
    for (int jt = 0; jt < TJQ / MT; jt += 2) {
      FragU ba, bb;
      ba.u = sB[g][jt * MT + m];
      bb.u = sB[g][(jt + 1) * MT + m];
      f32x16 da = __builtin_amdgcn_mfma_f32_32x32x16_bf16(af, ba.s, zc, 0, 0, 0);
      f32x16 db = __builtin_amdgcn_mfma_f32_32x32x16_bf16(af, bb.s, zc, 0, 0, 0);
#pragma unroll
      for (int r = 0; r < 16; ++r)
        run[r] = fminf(fminf(run[r], da[r]), db[r]);  // v_min3_f32
    }
  }

  // ---- epilogue: min across 32 cols, add |p|^2, atomicMin ----
  // C/D layout (m74/m101): col=lane&31, row=(reg&3)+8*(reg>>2)+4*(lane>>5)
#pragma unroll
  for (int r = 0; r < 16; ++r) {
    float v = run[r];
    v = fminf(v, __shfl_xor(v, 1));
    v = fminf(v, __shfl_xor(v, 2));
    v = fminf(v, __shfl_xor(v, 4));
    v = fminf(v, __shfl_xor(v, 8));
    v = fminf(v, __shfl_xor(v, 16));
    if (m == 0) {
      int row = (r & 3) + 8 * (r >> 2) + 4 * g;
      int il = w * MT + row;
      atomicMin(&um[ib0 + il], fmap(v + sNP[il]));
    }
  }
}

// Single-block final reduce: u holds complete squared distances; 256 KB
// coalesced uint4 reads, double accumulate, plain store (no out-memset node).
__global__ __launch_bounds__(1024) void cl_reduce(
    const unsigned int* __restrict__ u, float* __restrict__ out, int total) {
  const int t = threadIdx.x;
  const uint4* __restrict__ u4 = (const uint4*)u;
  double s = 0.0;
  for (int i = t; i < total / 4; i += 1024) {
    uint4 v = u4[i];
    s += (double)funmap(v.x) + (double)funmap(v.y) +
         (double)funmap(v.z) + (double)funmap(v.w);
  }
  for (int off = 32; off > 0; off >>= 1) s += __shfl_down(s, off, 64);
  __shared__ double sw[16];
  if ((t & 63) == 0) sw[t >> 6] = s;
  __syncthreads();
  if (t == 0) {
    double tot = 0.0;
    for (int wv = 0; wv < 16; ++wv) tot += sw[wv];
    out[0] = (float)(tot / (double)total);
  }
}

extern "C" void kernel_launch(void* const* d_in, const int* in_sizes, int n_in,
                              void* d_out, int out_size, void* d_ws, size_t ws_size,
                              hipStream_t stream) {
  const float* in_pc = (const float*)d_in[0];
  const float* tgt_pc = (const float*)d_in[1];
  const int B = 2, N = 16384;
  unsigned int* u = (unsigned int*)d_ws;  // [2][B][N] uints = 256 KB
  float* out = (float*)d_out;

  // 0xFF bytes == "+inf" under fmap ordering.
  hipMemsetAsync(u, 0xFF, (size_t)2 * B * N * sizeof(unsigned int), stream);

  const int jslice = N / SJ;             // 4096
  dim3 grid(N / IB, SJ, 2 * B);          // (64,4,4) = 1024 blocks x 512 thr
  cl_mfma<<<grid, dim3(BLK), 0, stream>>>(in_pc, tgt_pc, u, N, jslice, B);

  const int total = 2 * B * N;
  cl_reduce<<<dim3(1), dim3(1024), 0, stream>>>(u, out, total);
}